// Round 1
// baseline (18154.388 us; speedup 1.0000x reference)
//
#include <hip/hip_runtime.h>
#include <math.h>

#define SEQT 8192
#define HID  256
#define NTG  27
#define NEGV -10000.0f
#define START_TAG 25
#define STOP_TAG  26
#define T0B 16
#define T1B 32
#define VITBLK (T0B + T1B)
#define NBLKS  (T0B + T1B + 1)

// ---------- cross-XCD coherent helpers (L3 is the coherence point) ----------
__device__ __forceinline__ float agent_load(const float* p) {
  return __hip_atomic_load(const_cast<float*>(p), __ATOMIC_RELAXED, __HIP_MEMORY_SCOPE_AGENT);
}
__device__ __forceinline__ void agent_store(float* p, float v) {
  __hip_atomic_store(p, v, __ATOMIC_RELAXED, __HIP_MEMORY_SCOPE_AGENT);
}
// h values satisfy |h|<1 strictly; the 0x7F7F7F7F memset pattern (3.39e38) is
// an impossible value -> poll the data itself, no flags needed.
__device__ __forceinline__ float poll_val(const float* p, int* dead) {
  float v = agent_load(p);
  if (fabsf(v) < 2.0f) return v;
  if (*dead) return 0.0f;
  int ctr = 0;
  while (true) {
    __builtin_amdgcn_s_sleep(1);
    v = agent_load(p);
    if (fabsf(v) < 2.0f) return v;
    if (++ctr > (1 << 22)) { *dead = 1; return 0.0f; }  // dead-man valve
  }
}
__device__ __forceinline__ float sigm(float x) { return 1.0f / (1.0f + __expf(-x)); }
__device__ __forceinline__ float tanh_f(float x) {
  x = fminf(15.0f, fmaxf(-15.0f, x));   // avoid inf/inf NaN
  float e = __expf(-2.0f * x);
  return (1.0f - e) / (1.0f + e);
}

// ================= team 0 : layer-0 LSTM (emb gather + Wih fused) ==========
// 16 blocks x 512 thr. Block kb owns cells [16kb,16kb+16) -> 64 gate rows.
// thread = (qc = tid>>6 in [0,8), rl = tid&63). Chunk qc: h cols [32qc,32qc+32),
// x cols [16qc,16qc+16) (zero-padded past 100).
__device__ void team0_run(int kb, const int* sent, const float* emb,
                          const float* w_ih0, const float* w_hh0,
                          const float* b_ih0, const float* b_hh0,
                          float* h0hist) {
  __shared__ float hb[8 * 36];        // padded chunks: idx = 36*q + j (j<32)
  __shared__ float xb[2][8 * 20];     // padded chunks: idx = 20*q + j (j<16)
  __shared__ float part[512];
  __shared__ float preact[64];
  __shared__ int   deadf;

  const int tid = threadIdx.x;
  const int rl  = tid & 63;
  const int qc  = tid >> 6;
  const int grow = (rl >> 4) * 256 + kb * 16 + (rl & 15);  // gate*256 + cell

  float wh[32];
#pragma unroll
  for (int j = 0; j < 32; ++j) wh[j] = w_hh0[grow * 256 + qc * 32 + j];
  float wx[16];
#pragma unroll
  for (int j = 0; j < 16; ++j) {
    int c = qc * 16 + j;
    wx[j] = (c < 100) ? w_ih0[grow * 100 + c] : 0.0f;
  }
  float bsum = 0.0f, cst = 0.0f;
  if (tid < 64) bsum = b_ih0[grow] + b_hh0[grow];
  if (tid == 0) deadf = 0;

  if (tid >= 448) {                       // stage x_0
    int lane = tid - 448;
    int s0 = sent[0];
    for (int e = lane; e < 128; e += 64) {
      float v = (e < 100) ? emb[s0 * 100 + e] : 0.0f;
      xb[0][(e >> 4) * 20 + (e & 15)] = v;
    }
  }
  __syncthreads();

  for (int t = 0; t < SEQT; ++t) {
    const int par = t & 1;
    if (tid >= 256) {                     // fetch h_{t-1}
      int i = tid - 256;
      float v = (t == 0) ? 0.0f : poll_val(h0hist + (t - 1) * HID + i, &deadf);
      hb[(i >> 5) * 36 + (i & 31)] = v;
    }
    __syncthreads();                      // B1
    float acc = 0.0f;
    {
      const float4* h4 = (const float4*)(hb + qc * 36);
      const float4* x4 = (const float4*)(xb[par] + qc * 20);
#pragma unroll
      for (int m = 0; m < 8; ++m) {
        float4 h = h4[m];
        acc += wh[4*m+0]*h.x + wh[4*m+1]*h.y + wh[4*m+2]*h.z + wh[4*m+3]*h.w;
      }
#pragma unroll
      for (int m = 0; m < 4; ++m) {
        float4 x = x4[m];
        acc += wx[4*m+0]*x.x + wx[4*m+1]*x.y + wx[4*m+2]*x.z + wx[4*m+3]*x.w;
      }
    }
    part[tid] = acc;
    if (tid >= 448 && t + 1 < SEQT) {     // prefetch x_{t+1}
      int lane = tid - 448;
      int s0 = sent[t + 1];
      for (int e = lane; e < 128; e += 64) {
        float v = (e < 100) ? emb[s0 * 100 + e] : 0.0f;
        xb[par ^ 1][(e >> 4) * 20 + (e & 15)] = v;
      }
    }
    __syncthreads();                      // B2
    if (tid < 64) {
      float s = bsum;
#pragma unroll
      for (int q = 0; q < 8; ++q) s += part[q * 64 + tid];
      preact[tid] = s;
    }
    __syncthreads();                      // B3
    if (tid < 16) {
      float gi = sigm(preact[tid]);
      float gf = sigm(preact[16 + tid]);
      float gg = tanh_f(preact[32 + tid]);
      float go = sigm(preact[48 + tid]);
      cst = gf * cst + gi * gg;
      float h = go * tanh_f(cst);
      agent_store(h0hist + t * HID + kb * 16 + tid, h);
    }
  }
}

// ================= team 1 : layer-1 LSTM ===================================
// 32 blocks x 512 thr. Block kb owns cells [8kb,8kb+8) -> 32 gate rows.
// thread = (qc = tid>>5 in [0,16), rl = tid&31); chunk = 32 cols of [Wih1|Whh1].
__device__ void team1_run(int kb, const float* w_ih1, const float* w_hh1,
                          const float* b_ih1, const float* b_hh1,
                          const float* h0hist, float* h1hist) {
  __shared__ float hb[16 * 36];   // [h0_t | h1_{t-1}] padded
  __shared__ float part[512];
  __shared__ float preact[32];
  __shared__ int   deadf;

  const int tid = threadIdx.x;
  const int rl  = tid & 31;
  const int qc  = tid >> 5;
  const int grow = (rl >> 3) * 256 + kb * 8 + (rl & 7);

  float wc[32];
#pragma unroll
  for (int j = 0; j < 32; ++j) {
    int c = qc * 32 + j;
    wc[j] = (c < 256) ? w_ih1[grow * 256 + c] : w_hh1[grow * 256 + (c - 256)];
  }
  float bsum = 0.0f, cst = 0.0f;
  if (tid < 32) bsum = b_ih1[grow] + b_hh1[grow];
  if (tid == 0) deadf = 0;
  __syncthreads();

  for (int t = 0; t < SEQT; ++t) {
    {
      float v;
      if (tid < 256) v = poll_val(h0hist + t * HID + tid, &deadf);
      else v = (t == 0) ? 0.0f : poll_val(h1hist + (t - 1) * HID + (tid - 256), &deadf);
      hb[(tid >> 5) * 36 + (tid & 31)] = v;
    }
    __syncthreads();
    float acc = 0.0f;
    {
      const float4* h4 = (const float4*)(hb + qc * 36);
#pragma unroll
      for (int m = 0; m < 8; ++m) {
        float4 h = h4[m];
        acc += wc[4*m+0]*h.x + wc[4*m+1]*h.y + wc[4*m+2]*h.z + wc[4*m+3]*h.w;
      }
    }
    part[tid] = acc;
    __syncthreads();
    if (tid < 32) {
      float s = bsum;
#pragma unroll
      for (int q = 0; q < 16; ++q) s += part[q * 32 + tid];
      preact[tid] = s;
    }
    __syncthreads();
    if (tid < 8) {
      float gi = sigm(preact[tid]);
      float gf = sigm(preact[8 + tid]);
      float gg = tanh_f(preact[16 + tid]);
      float go = sigm(preact[24 + tid]);
      cst = gf * cst + gi * gg;
      float h = go * tanh_f(cst);
      agent_store(h1hist + t * HID + kb * 8 + tid, h);
    }
  }
}

// ================= block 48 : emissions + Viterbi + backtrace ==============
__device__ void viterbi_run(const int* amask, const float* w_lin, const float* b_lin,
                            const float* trans, const float* h1hist,
                            int* bp, float* out) {
  __shared__ float hb[8 * 36];
  __shared__ float spart[216];
  __shared__ float vbuf[NTG];
  __shared__ int   maps[128][NTG];
  __shared__ int   btag[129];
  __shared__ int   deadf;

  const int tid  = threadIdx.x;
  const int lane = tid & 63;
  const int stag = tid / 8, sq = tid % 8;      // score thread mapping (tid<216)

  float ws[32];
  if (tid < 216) {
#pragma unroll
    for (int j = 0; j < 32; ++j) ws[j] = w_lin[stag * 256 + sq * 32 + j];
  }
  float tcol[NTG]; float vreg = 0.0f, blin = 0.0f, tstop = 0.0f;
  if (tid < NTG) {
#pragma unroll
    for (int f = 0; f < NTG; ++f) tcol[f] = trans[f * NTG + tid];
    tstop = trans[tid * NTG + STOP_TAG];
    blin  = b_lin[tid];
    vreg  = (tid == START_TAG) ? 0.0f : NEGV;
    vbuf[tid] = vreg;
  }
  if (tid == 0) deadf = 0;
  float emit = 0.0f;
  __syncthreads();

  // software-pipelined: iteration it polls h1[it] + computes scores[it], while
  // wave0 performs the viterbi update for step it-1 with emit from last iter.
  for (int it = 0; it <= SEQT; ++it) {
    if (tid >= 256 && it < SEQT) {
      int i = tid - 256;
      float v = poll_val(h1hist + it * HID + i, &deadf);
      hb[(i >> 5) * 36 + (i & 31)] = v;
    }
    if (tid < NTG && it >= 1) {
      int tm1 = it - 1;
      int m = amask[tm1];
      float vf[NTG];
#pragma unroll
      for (int f = 0; f < NTG; ++f) vf[f] = vbuf[f];
      float best = -3.0e38f; int bpi = 0;
#pragma unroll
      for (int f = 0; f < NTG; ++f) {
        float c = vf[f] + tcol[f];
        if (c > best) { best = c; bpi = f; }   // strict > == np.argmax first-max
      }
      float vn   = best + emit;
      float vnew = m ? vn : vreg;
      int   bpv  = m ? bpi : tid;
      vreg = vnew;
      vbuf[tid] = vnew;
      bp[tm1 * NTG + tid] = bpv;
    }
    __syncthreads();
    if (tid < 216 && it < SEQT) {
      const float4* h4 = (const float4*)(hb + sq * 36);
      float acc = 0.0f;
#pragma unroll
      for (int m = 0; m < 8; ++m) {
        float4 h = h4[m];
        acc += ws[4*m+0]*h.x + ws[4*m+1]*h.y + ws[4*m+2]*h.z + ws[4*m+3]*h.w;
      }
      spart[tid] = acc;
    }
    __syncthreads();
    if (tid < NTG && it < SEQT) {
      float s = blin;
#pragma unroll
      for (int q = 0; q < 8; ++q) s += spart[tid * 8 + q];
      emit = s;
    }
  }
  __syncthreads();

  // terminal argmax (np.argmax tie-break: lowest index)
  if (tid < 64) {
    float tv = (lane < NTG) ? (vbuf[lane] + tstop) : -3.0e38f;
    int   ti = (lane < NTG) ? lane : NTG;
#pragma unroll
    for (int off = 32; off >= 1; off >>= 1) {
      float ov = __shfl_xor(tv, off);
      int   oi = __shfl_xor(ti, off);
      if ((ov > tv) || (ov == tv && oi < ti)) { tv = ov; ti = oi; }
    }
    if (lane == 0) { out[0] = tv; btag[128] = ti; }
  }
  __syncthreads();

  // per-64-step tag maps: 128 blocks x 27 end tags, 7 interleaved chains/thread
  {
    int bs[7], es[7], tg[7], nk = 0;
#pragma unroll
    for (int k = 0; k < 7; ++k) {
      int task = tid + k * 512;
      if (task < 128 * NTG) { bs[k] = task / NTG; es[k] = task % NTG; tg[k] = es[k]; nk = k + 1; }
      else { bs[k] = 0; es[k] = 0; tg[k] = 0; }
    }
    for (int i = 63; i >= 0; --i) {
#pragma unroll
      for (int k = 0; k < 7; ++k)
        if (k < nk) tg[k] = bp[(bs[k] * 64 + i) * NTG + tg[k]];
    }
#pragma unroll
    for (int k = 0; k < 7; ++k) if (k < nk) maps[bs[k]][es[k]] = tg[k];
  }
  __syncthreads();

  if (tid == 0) {              // boundary-tag chain over 128 blocks
    int e = btag[128];
    for (int b = 127; b >= 0; --b) { btag[b] = e; e = maps[b][e]; }
  }
  __syncthreads();

  if (tid < 128) {             // parallel per-block path reconstruction
    int b = tid, tag = btag[b];
    for (int i = 63; i >= 0; --i) {
      out[1 + b * 64 + i] = (float)tag;
      tag = bp[(b * 64 + i) * NTG + tag];
    }
  }
}

// ===========================================================================
__global__ __launch_bounds__(512, 1)
void lstm_crf_kernel(const int* sent, const int* amask, const float* emb,
                     const float* w_ih0, const float* w_hh0,
                     const float* b_ih0, const float* b_hh0,
                     const float* w_ih1, const float* w_hh1,
                     const float* b_ih1, const float* b_hh1,
                     const float* w_lin, const float* b_lin, const float* trans,
                     float* h0hist, float* h1hist, int* bp, float* out) {
  int b = blockIdx.x;
  if (b < T0B)       team0_run(b, sent, emb, w_ih0, w_hh0, b_ih0, b_hh0, h0hist);
  else if (b < VITBLK) team1_run(b - T0B, w_ih1, w_hh1, b_ih1, b_hh1, h0hist, h1hist);
  else               viterbi_run(amask, w_lin, b_lin, trans, h1hist, bp, out);
}

extern "C" void kernel_launch(void* const* d_in, const int* in_sizes, int n_in,
                              void* d_out, int out_size, void* d_ws, size_t ws_size,
                              hipStream_t stream) {
  const int*   sent  = (const int*)d_in[0];
  const int*   amask = (const int*)d_in[1];
  const float* emb   = (const float*)d_in[2];
  const float* w_ih0 = (const float*)d_in[3];
  const float* w_hh0 = (const float*)d_in[4];
  const float* b_ih0 = (const float*)d_in[5];
  const float* b_hh0 = (const float*)d_in[6];
  const float* w_ih1 = (const float*)d_in[7];
  const float* w_hh1 = (const float*)d_in[8];
  const float* b_ih1 = (const float*)d_in[9];
  const float* b_hh1 = (const float*)d_in[10];
  const float* w_lin = (const float*)d_in[11];
  const float* b_lin = (const float*)d_in[12];
  const float* trans = (const float*)d_in[13];

  float* h0hist = (float*)d_ws;
  float* h1hist = h0hist + (size_t)SEQT * HID;
  int*   bp     = (int*)(h1hist + (size_t)SEQT * HID);
  float* out    = (float*)d_out;

  // re-arm the sentinel pattern every call (0x7F7F7F7F = 3.39e38, impossible h)
  (void)hipMemsetAsync(d_ws, 0x7F, (size_t)2 * SEQT * HID * sizeof(float), stream);

  lstm_crf_kernel<<<NBLKS, 512, 0, stream>>>(
      sent, amask, emb, w_ih0, w_hh0, b_ih0, b_hh0,
      w_ih1, w_hh1, b_ih1, b_hh1, w_lin, b_lin, trans,
      h0hist, h1hist, bp, out);
}